// Round 7
// baseline (131.823 us; speedup 1.0000x reference)
//
#include <hip/hip_runtime.h>

// Problem constants: B=2, T=2048, C=1024, H=16, S=64
#define BB 2
#define TT 2048
#define CC 1024
#define HH 16
#define SS 64
#define MM (BB * TT)   // 4096

typedef unsigned short u16;
typedef __bf16 bf16x8 __attribute__((ext_vector_type(8)));
typedef float f32x4 __attribute__((ext_vector_type(4)));
typedef float f32x16 __attribute__((ext_vector_type(16)));

#define MFMA16(a, b, c) __builtin_amdgcn_mfma_f32_16x16x32_bf16((a), (b), (c), 0, 0, 0)
#define MFMA32(a, b, c) __builtin_amdgcn_mfma_f32_32x32x16_bf16((a), (b), (c), 0, 0, 0)
// v_cvt_pk_bf16_f32: D[15:0]=bf16(S0), D[31:16]=bf16(S1)
#define CVTPK(d, a, b) asm("v_cvt_pk_bf16_f32 %0, %1, %2" : "=v"(d) : "v"(a), "v"(b))

__device__ inline u16 f2bf(float f) {
    union { float f; unsigned u; } v;
    v.f = f;
    unsigned r = v.u + 0x7FFFu + ((v.u >> 16) & 1u);
    return (u16)(r >> 16);
}

// ---------------------------------------------------------------- fused casts
__global__ __launch_bounds__(256) void cast_all(
    const float4* __restrict__ x,  const float4* __restrict__ wq,
    const float4* __restrict__ wk, const float4* __restrict__ wv,
    const float4* __restrict__ wo,
    ushort4* __restrict__ xo, ushort4* __restrict__ qo,
    ushort4* __restrict__ ko, ushort4* __restrict__ vo,
    ushort4* __restrict__ oo) {
    int bid = blockIdx.x;
    const float4* src; ushort4* dst; int i;
    if (bid < 4096) {
        src = x; dst = xo; i = bid * 256 + threadIdx.x;
    } else {
        int s = (bid - 4096) >> 10;
        int r = (bid - 4096) & 1023;
        src = (s == 0) ? wq : (s == 1) ? wk : (s == 2) ? wv : wo;
        dst = (s == 0) ? qo : (s == 1) ? ko : (s == 2) ? vo : oo;
        i = r * 256 + threadIdx.x;
    }
    float4 v = src[i];
    ushort4 o;
    o.x = f2bf(v.x); o.y = f2bf(v.y); o.z = f2bf(v.z); o.w = f2bf(v.w);
    dst[i] = o;
}

// ---------------------------------------------------------------- 128x128 GEMM core
__device__ __forceinline__ void stage_tile(const u16* __restrict__ g, int row0, int k0,
                                           u16* lds) {
    int t = threadIdx.x;
#pragma unroll
    for (int q = 0; q < 2; ++q) {
        int idx = q * 256 + t;
        int row = idx >> 2;
        int chunk = (idx & 3) ^ (row & 3);
        const u16* src = g + (long)(row0 + row) * CC + k0 + chunk * 8;
        __builtin_amdgcn_global_load_lds(
            (const __attribute__((address_space(1))) void*)src,
            (__attribute__((address_space(3))) void*)(lds + idx * 8), 16, 0, 0);
    }
}

__device__ __forceinline__ void gemm_core(const u16* __restrict__ A,
                                          const u16* __restrict__ Bt,
                                          int blkM, int blkN,
                                          u16* sA0, u16* sB0, u16* sA1, u16* sB1,
                                          f32x4 (&acc)[4][4]) {
    int lane = threadIdx.x & 63;
    int w = threadIdx.x >> 6;
    int wr = w >> 1, wc = w & 1;
    int l15 = lane & 15;
    int hi = lane >> 4;

#pragma unroll
    for (int m = 0; m < 4; ++m)
#pragma unroll
        for (int n = 0; n < 4; ++n) acc[m][n] = (f32x4){0.f, 0.f, 0.f, 0.f};

    stage_tile(A, blkM * 128, 0, sA0);
    stage_tile(Bt, blkN * 128, 0, sB0);

    for (int kt = 0; kt < CC / 32; ++kt) {
        __syncthreads();
        u16* cA = (kt & 1) ? sA1 : sA0;
        u16* cB = (kt & 1) ? sB1 : sB0;
        if (kt + 1 < CC / 32) {
            u16* nA = (kt & 1) ? sA0 : sA1;
            u16* nB = (kt & 1) ? sB0 : sB1;
            stage_tile(A, blkM * 128, (kt + 1) * 32, nA);
            stage_tile(Bt, blkN * 128, (kt + 1) * 32, nB);
        }
        bf16x8 af[4], bfr[4];
#pragma unroll
        for (int m = 0; m < 4; ++m) {
            int row = wr * 64 + m * 16 + l15;
            af[m] = *(const bf16x8*)(cA + row * 32 + ((hi ^ (row & 3)) << 3));
        }
#pragma unroll
        for (int n = 0; n < 4; ++n) {
            int row = wc * 64 + n * 16 + l15;
            bfr[n] = *(const bf16x8*)(cB + row * 32 + ((hi ^ (row & 3)) << 3));
        }
#pragma unroll
        for (int m = 0; m < 4; ++m)
#pragma unroll
            for (int n = 0; n < 4; ++n)
                acc[m][n] = MFMA16(af[m], bfr[n], acc[m][n]);
    }
}

__global__ __launch_bounds__(256) void qkv_gemm(const u16* __restrict__ xb,
                                                const u16* __restrict__ wqb,
                                                const u16* __restrict__ wkb,
                                                const u16* __restrict__ wvb,
                                                u16* __restrict__ qo,
                                                u16* __restrict__ ko,
                                                u16* __restrict__ vt) {
    __shared__ u16 smem[4][128 * 32];
    int seg = blockIdx.x >> 8;
    int bid = blockIdx.x & 255;
    int blkM = bid & 31, blkN = bid >> 5;
    const u16* Bt = (seg == 0) ? wqb : (seg == 1) ? wkb : wvb;
    f32x4 acc[4][4];
    gemm_core(xb, Bt, blkM, blkN, smem[0], smem[1], smem[2], smem[3], acc);

    int lane = threadIdx.x & 63;
    int w = threadIdx.x >> 6, wr = w >> 1, wc = w & 1;
    int l15 = lane & 15, hi = lane >> 4;
    int r0 = blkM * 128 + wr * 64 + hi * 4;
    int c0 = blkN * 128 + wc * 64 + l15;

    if (seg == 2) {
#pragma unroll
        for (int m = 0; m < 4; ++m)
#pragma unroll
            for (int n = 0; n < 4; ++n) {
                ushort4 p;
                p.x = f2bf(acc[m][n][0]); p.y = f2bf(acc[m][n][1]);
                p.z = f2bf(acc[m][n][2]); p.w = f2bf(acc[m][n][3]);
                *(ushort4*)(vt + (long)(c0 + n * 16) * MM + r0 + m * 16) = p;
            }
    } else {
        u16* dst = (seg == 0) ? qo : ko;
        // Q pre-scaled by 1/sqrt(64) * log2(e): exp2-domain softmax
        float sc = (seg == 0) ? 0.18033688011112042f : 1.0f;
#pragma unroll
        for (int m = 0; m < 4; ++m)
#pragma unroll
            for (int n = 0; n < 4; ++n)
#pragma unroll
                for (int i = 0; i < 4; ++i)
                    dst[(long)(r0 + m * 16 + i) * CC + c0 + n * 16] =
                        f2bf(acc[m][n][i] * sc);
    }
}

__global__ __launch_bounds__(256) void out_gemm(const u16* __restrict__ at,
                                                const u16* __restrict__ wob,
                                                const float* __restrict__ bias,
                                                float* __restrict__ out) {
    __shared__ u16 smem[4][128 * 32];
    int bid = blockIdx.x;
    int blkM = bid & 31, blkN = bid >> 5;
    f32x4 acc[4][4];
    gemm_core(at, wob, blkM, blkN, smem[0], smem[1], smem[2], smem[3], acc);

    int lane = threadIdx.x & 63;
    int w = threadIdx.x >> 6, wr = w >> 1, wc = w & 1;
    int l15 = lane & 15, hi = lane >> 4;
    int r0 = blkM * 128 + wr * 64 + hi * 4;
    int c0 = blkN * 128 + wc * 64 + l15;
#pragma unroll
    for (int n = 0; n < 4; ++n) {
        int c = c0 + n * 16;
        float bv = bias[c];
#pragma unroll
        for (int m = 0; m < 4; ++m)
#pragma unroll
            for (int i = 0; i < 4; ++i)
                out[(long)(r0 + m * 16 + i) * CC + c] = acc[m][n][i] + bv;
    }
}

// ---------------------------------------------------------------- flash attention v7
// v6 mechanics, 4 waves/block. Wave w owns interleaved q-rows qg = 128p + 4*l31 + w,
// so ALL waves need the same ntiles = 2p+2 KV tiles (uniform barriers, balanced).
// K/V staged once per block (2x reuse vs v6), LDS dbuf, XCD-local bh, LPT order.
__device__ __forceinline__ void stage_kv4(const u16* __restrict__ Kg,
                                          const u16* __restrict__ Vg,
                                          u16* dK, u16* dV) {
    int t = threadIdx.x;   // 0..255
#pragma unroll
    for (int q = 0; q < 2; ++q) {
        int c = q * 256 + t;           // 16B chunk 0..511
        int row = c >> 3, col = c & 7;
        int scol = col ^ (row & 7);
        __builtin_amdgcn_global_load_lds(
            (const __attribute__((address_space(1))) void*)(Kg + (long)row * CC + scol * 8),
            (__attribute__((address_space(3))) void*)(dK + c * 8), 16, 0, 0);
        __builtin_amdgcn_global_load_lds(
            (const __attribute__((address_space(1))) void*)(Vg + (long)row * MM + scol * 8),
            (__attribute__((address_space(3))) void*)(dV + c * 8), 16, 0, 0);
    }
}

#define PSTR 68   // P row stride (u16): 136B -> 8B-aligned stores, ~2-way banks

__global__ __launch_bounds__(256) void attn_fwd(const u16* __restrict__ Q,
                                                const u16* __restrict__ Kb,
                                                const u16* __restrict__ Vt,
                                                u16* __restrict__ O) {
    __shared__ u16 sK[2][64 * 64];
    __shared__ u16 sV[2][64 * 64];
    __shared__ u16 sP[4][32 * PSTR];
    int lane = threadIdx.x & 63;
    int w = threadIdx.x >> 6;           // 0..3
    int bh = blockIdx.x & 31;           // same bh -> same XCD (idx&7 = bh&7)
    int pp = 15 - (blockIdx.x >> 5);    // 128-row q-block, heaviest first (LPT)
    int h = bh & 15, b = bh >> 4;
    int l31 = lane & 31, h5 = lane >> 5;

    int qg = 128 * pp + 4 * l31 + w;    // this lane's q row (interleaved by wave)
    int ntiles = 2 * pp + 2;

    const u16* Kgb = Kb + (long)(b * TT) * CC + h * SS;
    const u16* Vgb = Vt + (long)(h * SS) * MM + b * TT;
    u16* Pw = sP[w];

    // Q fragments (B operand): col=l31 (q), k = m*16 + h5*8 + j
    const u16* qrow = Q + (long)(b * TT + qg) * CC + h * SS + h5 * 8;
    bf16x8 qf[4];
#pragma unroll
    for (int m = 0; m < 4; ++m) qf[m] = *(const bf16x8*)(qrow + m * 16);

    f32x16 oa0 = {0.f}, oa1 = {0.f};    // O^T accum: d 0..31 / 32..63, col=q=l31
    float mr = -1e30f, lr = 0.f;

    stage_kv4(Kgb, Vgb, sK[0], sV[0]);

#pragma unroll 1
    for (int t = 0; t < ntiles; ++t) {
        __syncthreads();   // vmcnt drained -> buf[t&1] ready; prev reads fenced
        const u16* cK = sK[t & 1];
        const u16* cV = sV[t & 1];
        if (t + 1 < ntiles)
            stage_kv4(Kgb + (long)(t + 1) * 64 * CC, Vgb + (t + 1) * 64,
                      sK[(t + 1) & 1], sV[(t + 1) & 1]);

        // QK^T swapped: S^T = mfma(A=K, B=Q). s0: kv 0..31, s1: kv 32..63.
        f32x16 s0 = {0.f}, s1 = {0.f};
#pragma unroll
        for (int m = 0; m < 4; ++m) {
            int ch0 = (((m * 2 + h5) ^ (l31 & 7)) << 3);
            bf16x8 k0 = *(const bf16x8*)(cK + l31 * 64 + ch0);
            bf16x8 k1 = *(const bf16x8*)(cK + (32 + l31) * 64 + ch0);
            s0 = MFMA32(k0, qf[m], s0);
            s1 = MFMA32(k1, qf[m], s1);
        }

        if (t >= 2 * pp) {   // last two tiles overlap the causal diagonal
            int kvb = t * 64 + 4 * h5;
#pragma unroll
            for (int r = 0; r < 16; ++r) {
                int kv = kvb + (r & 3) + 8 * (r >> 2);
                if (kv > qg) s0[r] = -1e30f;
                if (kv + 32 > qg) s1[r] = -1e30f;
            }
        }

        // tile max: in-lane tree + one partner exchange
        f32x16 m2;
#pragma unroll
        for (int r = 0; r < 16; ++r) m2[r] = fmaxf(s0[r], s1[r]);
#pragma unroll
        for (int r = 0; r < 8; ++r) m2[r] = fmaxf(m2[r], m2[r + 8]);
#pragma unroll
        for (int r = 0; r < 4; ++r) m2[r] = fmaxf(m2[r], m2[r + 4]);
        float tmx = fmaxf(fmaxf(m2[0], m2[1]), fmaxf(m2[2], m2[3]));
        tmx = fmaxf(tmx, __shfl_xor(tmx, 32));

        // defer-max: rescale only when tile max exceeds running max by > 8
        if (!__all(tmx <= mr + 8.0f)) {
            float mnew = fmaxf(mr, tmx);
            float scl = __builtin_amdgcn_exp2f(mr - mnew);
            lr *= scl;
#pragma unroll
            for (int r = 0; r < 16; ++r) { oa0[r] *= scl; oa1[r] *= scl; }
            mr = mnew;
        }

        // P = exp2(S - mr), bounded by 2^8
        f32x16 p0v, p1v;
#pragma unroll
        for (int r = 0; r < 16; ++r) {
            p0v[r] = __builtin_amdgcn_exp2f(s0[r] - mr);
            p1v[r] = __builtin_amdgcn_exp2f(s1[r] - mr);
        }
        f32x16 sm;
#pragma unroll
        for (int r = 0; r < 16; ++r) sm[r] = p0v[r] + p1v[r];
#pragma unroll
        for (int r = 0; r < 8; ++r) sm[r] = sm[r] + sm[r + 8];
#pragma unroll
        for (int r = 0; r < 4; ++r) sm[r] = sm[r] + sm[r + 4];
        float rs = (sm[0] + sm[1]) + (sm[2] + sm[3]);
        rs += __shfl_xor(rs, 32);
        lr += rs;

        // P -> LDS [q=l31][kv], stride PSTR; packed via cvt_pk (low u16 = src0)
#pragma unroll
        for (int r4 = 0; r4 < 4; ++r4) {
            unsigned a0, a1, c0, c1;
            CVTPK(a0, p0v[r4 * 4 + 0], p0v[r4 * 4 + 1]);
            CVTPK(a1, p0v[r4 * 4 + 2], p0v[r4 * 4 + 3]);
            CVTPK(c0, p1v[r4 * 4 + 0], p1v[r4 * 4 + 1]);
            CVTPK(c1, p1v[r4 * 4 + 2], p1v[r4 * 4 + 3]);
            uint2 ua, uc;
            ua.x = a0; ua.y = a1; uc.x = c0; uc.y = c1;
            *(uint2*)(Pw + l31 * PSTR + 8 * r4 + 4 * h5) = ua;
            *(uint2*)(Pw + l31 * PSTR + 32 + 8 * r4 + 4 * h5) = uc;
        }
        asm volatile("s_waitcnt lgkmcnt(0)" ::: "memory");
        __builtin_amdgcn_sched_barrier(0);

        // PV: O^T[d][q] += V[d][kv] * P^T[kv][q]; B-frag read: kv = 16s + 8*h5 + j
#pragma unroll
        for (int s = 0; s < 4; ++s) {
            bf16x8 pf = *(const bf16x8*)(Pw + l31 * PSTR + 16 * s + 8 * h5);
            int ch = (((2 * s + h5) ^ (l31 & 7)) << 3);
            bf16x8 v0 = *(const bf16x8*)(cV + l31 * 64 + ch);
            bf16x8 v1 = *(const bf16x8*)(cV + (32 + l31) * 64 + ch);
            oa0 = MFMA32(v0, pf, oa0);
            oa1 = MFMA32(v1, pf, oa1);
        }
    }

    // store O^T -> O[q][d]: oa0[r] = d (r&3)+8*(r>>2)+4*h5, col q = l31
    float inv = 1.0f / lr;
    u16* ob = O + (long)(b * TT + qg) * CC + h * SS;
#pragma unroll
    for (int rq = 0; rq < 4; ++rq) {
        unsigned a0, a1, c0, c1;
        CVTPK(a0, oa0[rq * 4 + 0] * inv, oa0[rq * 4 + 1] * inv);
        CVTPK(a1, oa0[rq * 4 + 2] * inv, oa0[rq * 4 + 3] * inv);
        CVTPK(c0, oa1[rq * 4 + 0] * inv, oa1[rq * 4 + 1] * inv);
        CVTPK(c1, oa1[rq * 4 + 2] * inv, oa1[rq * 4 + 3] * inv);
        uint2 ua, uc;
        ua.x = a0; ua.y = a1; uc.x = c0; uc.y = c1;
        *(uint2*)(ob + rq * 8 + h5 * 4) = ua;
        *(uint2*)(ob + 32 + rq * 8 + h5 * 4) = uc;
    }
}

// ---------------------------------------------------------------- launch
extern "C" void kernel_launch(void* const* d_in, const int* in_sizes, int n_in,
                              void* d_out, int out_size, void* d_ws, size_t ws_size,
                              hipStream_t stream) {
    const float* x  = (const float*)d_in[0];
    const float* Wq = (const float*)d_in[1];
    const float* Wk = (const float*)d_in[2];
    const float* Wv = (const float*)d_in[3];
    const float* Wo = (const float*)d_in[4];
    const float* bo = (const float*)d_in[5];

    char* ws = (char*)d_ws;
    const size_t MB = 1024 * 1024;
    u16* x_bf  = (u16*)(ws);
    u16* wq_bf = (u16*)(ws + 8 * MB);
    u16* wk_bf = (u16*)(ws + 10 * MB);
    u16* wv_bf = (u16*)(ws + 12 * MB);
    u16* wo_bf = (u16*)(ws + 14 * MB);
    u16* q_bf  = (u16*)(ws + 16 * MB);
    u16* k_bf  = (u16*)(ws + 24 * MB);
    u16* vt_bf = (u16*)(ws + 32 * MB);   // [1024][4096] transposed V
    u16* at_bf = (u16*)(ws + 40 * MB);

    cast_all<<<dim3(8192), dim3(256), 0, stream>>>(
        (const float4*)x, (const float4*)Wq, (const float4*)Wk,
        (const float4*)Wv, (const float4*)Wo,
        (ushort4*)x_bf, (ushort4*)wq_bf, (ushort4*)wk_bf,
        (ushort4*)wv_bf, (ushort4*)wo_bf);

    qkv_gemm<<<dim3(768), dim3(256), 0, stream>>>(x_bf, wq_bf, wk_bf, wv_bf,
                                                  q_bf, k_bf, vt_bf);

    attn_fwd<<<dim3(512), dim3(256), 0, stream>>>(q_bf, k_bf, vt_bf, at_bf);

    out_gemm<<<dim3(256), dim3(256), 0, stream>>>(at_bf, wo_bf, bo, (float*)d_out);
}

// Round 8
// 118.061 us; speedup vs baseline: 1.1166x; 1.1166x over previous
//
#include <hip/hip_runtime.h>

// Problem constants: B=2, T=2048, C=1024, H=16, S=64
#define BB 2
#define TT 2048
#define CC 1024
#define HH 16
#define SS 64
#define MM (BB * TT)   // 4096

typedef unsigned short u16;
typedef __bf16 bf16x8 __attribute__((ext_vector_type(8)));
typedef float f32x4 __attribute__((ext_vector_type(4)));
typedef float f32x16 __attribute__((ext_vector_type(16)));

#define MFMA16(a, b, c) __builtin_amdgcn_mfma_f32_16x16x32_bf16((a), (b), (c), 0, 0, 0)
#define MFMA32(a, b, c) __builtin_amdgcn_mfma_f32_32x32x16_bf16((a), (b), (c), 0, 0, 0)
// v_cvt_pk_bf16_f32: D[15:0]=bf16(S0), D[31:16]=bf16(S1)
#define CVTPK(d, a, b) asm("v_cvt_pk_bf16_f32 %0, %1, %2" : "=v"(d) : "v"(a), "v"(b))

__device__ inline u16 f2bf(float f) {
    union { float f; unsigned u; } v;
    v.f = f;
    unsigned r = v.u + 0x7FFFu + ((v.u >> 16) & 1u);
    return (u16)(r >> 16);
}

// ---------------------------------------------------------------- fused casts
__global__ __launch_bounds__(256) void cast_all(
    const float4* __restrict__ x,  const float4* __restrict__ wq,
    const float4* __restrict__ wk, const float4* __restrict__ wv,
    const float4* __restrict__ wo,
    ushort4* __restrict__ xo, ushort4* __restrict__ qo,
    ushort4* __restrict__ ko, ushort4* __restrict__ vo,
    ushort4* __restrict__ oo) {
    int bid = blockIdx.x;
    const float4* src; ushort4* dst; int i;
    if (bid < 4096) {
        src = x; dst = xo; i = bid * 256 + threadIdx.x;
    } else {
        int s = (bid - 4096) >> 10;
        int r = (bid - 4096) & 1023;
        src = (s == 0) ? wq : (s == 1) ? wk : (s == 2) ? wv : wo;
        dst = (s == 0) ? qo : (s == 1) ? ko : (s == 2) ? vo : oo;
        i = r * 256 + threadIdx.x;
    }
    float4 v = src[i];
    ushort4 o;
    o.x = f2bf(v.x); o.y = f2bf(v.y); o.z = f2bf(v.z); o.w = f2bf(v.w);
    dst[i] = o;
}

// ---------------------------------------------------------------- 128x128 GEMM core
__device__ __forceinline__ void stage_tile(const u16* __restrict__ g, int row0, int k0,
                                           u16* lds) {
    int t = threadIdx.x;
#pragma unroll
    for (int q = 0; q < 2; ++q) {
        int idx = q * 256 + t;
        int row = idx >> 2;
        int chunk = (idx & 3) ^ (row & 3);
        const u16* src = g + (long)(row0 + row) * CC + k0 + chunk * 8;
        __builtin_amdgcn_global_load_lds(
            (const __attribute__((address_space(1))) void*)src,
            (__attribute__((address_space(3))) void*)(lds + idx * 8), 16, 0, 0);
    }
}

__device__ __forceinline__ void gemm_core(const u16* __restrict__ A,
                                          const u16* __restrict__ Bt,
                                          int blkM, int blkN,
                                          u16* sA0, u16* sB0, u16* sA1, u16* sB1,
                                          f32x4 (&acc)[4][4]) {
    int lane = threadIdx.x & 63;
    int w = threadIdx.x >> 6;
    int wr = w >> 1, wc = w & 1;
    int l15 = lane & 15;
    int hi = lane >> 4;

#pragma unroll
    for (int m = 0; m < 4; ++m)
#pragma unroll
        for (int n = 0; n < 4; ++n) acc[m][n] = (f32x4){0.f, 0.f, 0.f, 0.f};

    stage_tile(A, blkM * 128, 0, sA0);
    stage_tile(Bt, blkN * 128, 0, sB0);

    for (int kt = 0; kt < CC / 32; ++kt) {
        __syncthreads();
        u16* cA = (kt & 1) ? sA1 : sA0;
        u16* cB = (kt & 1) ? sB1 : sB0;
        if (kt + 1 < CC / 32) {
            u16* nA = (kt & 1) ? sA0 : sA1;
            u16* nB = (kt & 1) ? sB0 : sB1;
            stage_tile(A, blkM * 128, (kt + 1) * 32, nA);
            stage_tile(Bt, blkN * 128, (kt + 1) * 32, nB);
        }
        bf16x8 af[4], bfr[4];
#pragma unroll
        for (int m = 0; m < 4; ++m) {
            int row = wr * 64 + m * 16 + l15;
            af[m] = *(const bf16x8*)(cA + row * 32 + ((hi ^ (row & 3)) << 3));
        }
#pragma unroll
        for (int n = 0; n < 4; ++n) {
            int row = wc * 64 + n * 16 + l15;
            bfr[n] = *(const bf16x8*)(cB + row * 32 + ((hi ^ (row & 3)) << 3));
        }
#pragma unroll
        for (int m = 0; m < 4; ++m)
#pragma unroll
            for (int n = 0; n < 4; ++n)
                acc[m][n] = MFMA16(af[m], bfr[n], acc[m][n]);
    }
}

__global__ __launch_bounds__(256) void qkv_gemm(const u16* __restrict__ xb,
                                                const u16* __restrict__ wqb,
                                                const u16* __restrict__ wkb,
                                                const u16* __restrict__ wvb,
                                                u16* __restrict__ qo,
                                                u16* __restrict__ ko,
                                                u16* __restrict__ vt) {
    __shared__ u16 smem[4][128 * 32];
    int seg = blockIdx.x >> 8;
    int bid = blockIdx.x & 255;
    int blkM = bid & 31, blkN = bid >> 5;
    const u16* Bt = (seg == 0) ? wqb : (seg == 1) ? wkb : wvb;
    f32x4 acc[4][4];
    gemm_core(xb, Bt, blkM, blkN, smem[0], smem[1], smem[2], smem[3], acc);

    int lane = threadIdx.x & 63;
    int w = threadIdx.x >> 6, wr = w >> 1, wc = w & 1;
    int l15 = lane & 15, hi = lane >> 4;
    int r0 = blkM * 128 + wr * 64 + hi * 4;
    int c0 = blkN * 128 + wc * 64 + l15;

    if (seg == 2) {
#pragma unroll
        for (int m = 0; m < 4; ++m)
#pragma unroll
            for (int n = 0; n < 4; ++n) {
                ushort4 p;
                p.x = f2bf(acc[m][n][0]); p.y = f2bf(acc[m][n][1]);
                p.z = f2bf(acc[m][n][2]); p.w = f2bf(acc[m][n][3]);
                *(ushort4*)(vt + (long)(c0 + n * 16) * MM + r0 + m * 16) = p;
            }
    } else {
        u16* dst = (seg == 0) ? qo : ko;
        // Q pre-scaled by 1/sqrt(64) * log2(e): exp2-domain softmax
        float sc = (seg == 0) ? 0.18033688011112042f : 1.0f;
#pragma unroll
        for (int m = 0; m < 4; ++m)
#pragma unroll
            for (int n = 0; n < 4; ++n)
#pragma unroll
                for (int i = 0; i < 4; ++i)
                    dst[(long)(r0 + m * 16 + i) * CC + c0 + n * 16] =
                        f2bf(acc[m][n][i] * sc);
    }
}

__global__ __launch_bounds__(256) void out_gemm(const u16* __restrict__ at,
                                                const u16* __restrict__ wob,
                                                const float* __restrict__ bias,
                                                float* __restrict__ out) {
    __shared__ u16 smem[4][128 * 32];
    int bid = blockIdx.x;
    int blkM = bid & 31, blkN = bid >> 5;
    f32x4 acc[4][4];
    gemm_core(at, wob, blkM, blkN, smem[0], smem[1], smem[2], smem[3], acc);

    int lane = threadIdx.x & 63;
    int w = threadIdx.x >> 6, wr = w >> 1, wc = w & 1;
    int l15 = lane & 15, hi = lane >> 4;
    int r0 = blkM * 128 + wr * 64 + hi * 4;
    int c0 = blkN * 128 + wc * 64 + l15;
#pragma unroll
    for (int n = 0; n < 4; ++n) {
        int c = c0 + n * 16;
        float bv = bias[c];
#pragma unroll
        for (int m = 0; m < 4; ++m)
#pragma unroll
            for (int i = 0; i < 4; ++i)
                out[(long)(r0 + m * 16 + i) * CC + c] = acc[m][n][i] + bv;
    }
}

// ---------------------------------------------------------------- flash attention v8
// Split-KV: block = 2 waves, BOTH handle the same 32 q-rows (qt). Each iteration
// stages one 64-kv K/V pair; wave 0 consumes kv rows 0..31, wave 1 rows 32..63.
// Partial (m, l, O) merged via one LDS exchange at the end. 2048 blocks = 4096
// waves (2x v6 parallelism), ~21 KB LDS -> 7 blocks/CU resident.
#define PSTR2 36   // P row stride (u16): 72B, 8B-aligned

__global__ __launch_bounds__(128) void attn_fwd(const u16* __restrict__ Q,
                                                const u16* __restrict__ Kb,
                                                const u16* __restrict__ Vt,
                                                u16* __restrict__ O) {
    __shared__ u16 sKV[2 * 64 * 64];            // K tile | V tile (16 KB)
    __shared__ u16 sP[2][32 * PSTR2];
    u16* sK = sKV;
    u16* sV = sKV + 64 * 64;

    int lane = threadIdx.x & 63;
    int w = threadIdx.x >> 6;           // 0..1 = kv-half of each staged tile
    int bh = blockIdx.x & 31;           // same bh -> same XCD (idx&7 = bh&7)
    int qt = 63 - (blockIdx.x >> 5);    // q-tile of 32 rows, heaviest first (LPT)
    int h = bh & 15, b = bh >> 4;
    int l31 = lane & 31, h5 = lane >> 5;

    int qg = qt * 32 + l31;             // this lane's q row
    int nt32 = qt + 1;                  // 32-kv subtiles needed
    int J = (qt >> 1) + 1;              // staged 64-kv iterations (uniform)

    const u16* Kgb = Kb + (long)(b * TT) * CC + h * SS;
    const u16* Vgb = Vt + (long)(h * SS) * MM + b * TT;
    u16* Pw = sP[w];

    // Q fragments (B operand): col=l31 (q), k = m*16 + h5*8 + j
    const u16* qrow = Q + (long)(b * TT + qg) * CC + h * SS + h5 * 8;
    bf16x8 qf[4];
#pragma unroll
    for (int m = 0; m < 4; ++m) qf[m] = *(const bf16x8*)(qrow + m * 16);

    f32x16 oa0 = {0.f}, oa1 = {0.f};    // O^T partial: d 0..31 / 32..63, col=q=l31
    float mr = -1e30f, lr = 0.f;

#pragma unroll 1
    for (int j = 0; j < J; ++j) {
        // stage 64-kv K/V pair at kv0 = 64j (128 threads, 8 chunks each)
        {
            int t = threadIdx.x;
            const u16* Kg = Kgb + (long)(64 * j) * CC;
            const u16* Vg = Vgb + 64 * j;
#pragma unroll
            for (int q = 0; q < 4; ++q) {
                int c = q * 128 + t;           // 16B chunk 0..511
                int row = c >> 3, col = c & 7;
                int scol = col ^ (row & 7);
                __builtin_amdgcn_global_load_lds(
                    (const __attribute__((address_space(1))) void*)(Kg + (long)row * CC + scol * 8),
                    (__attribute__((address_space(3))) void*)(sK + c * 8), 16, 0, 0);
                __builtin_amdgcn_global_load_lds(
                    (const __attribute__((address_space(1))) void*)(Vg + (long)row * MM + scol * 8),
                    (__attribute__((address_space(3))) void*)(sV + c * 8), 16, 0, 0);
            }
        }
        __syncthreads();   // vmcnt drained -> tiles ready; prev P reads fenced

        int tt = 2 * j + w;            // this wave's 32-kv subtile index
        if (tt < nt32) {
            // QK^T swapped: S^T = mfma(A=K rows w*32+l31, B=Q)
            f32x16 s0 = {0.f};
#pragma unroll
            for (int m = 0; m < 4; ++m) {
                int ch0 = (((m * 2 + h5) ^ (l31 & 7)) << 3);
                bf16x8 kf = *(const bf16x8*)(sK + (w * 32 + l31) * 64 + ch0);
                s0 = MFMA32(kf, qf[m], s0);
            }

            if (tt == qt) {   // diagonal subtile: causal mask (kv > q)
                int kvb = tt * 32 + 4 * h5;
#pragma unroll
                for (int r = 0; r < 16; ++r) {
                    int kv = kvb + (r & 3) + 8 * (r >> 2);
                    if (kv > qg) s0[r] = -1e30f;
                }
            }

            // subtile max: in-lane tree + one partner exchange
            float t8[8];
#pragma unroll
            for (int r = 0; r < 8; ++r) t8[r] = fmaxf(s0[r], s0[r + 8]);
#pragma unroll
            for (int r = 0; r < 4; ++r) t8[r] = fmaxf(t8[r], t8[r + 4]);
            float tmx = fmaxf(fmaxf(t8[0], t8[1]), fmaxf(t8[2], t8[3]));
            tmx = fmaxf(tmx, __shfl_xor(tmx, 32));

            // defer-max: rescale only when subtile max exceeds running max by > 8
            if (!__all(tmx <= mr + 8.0f)) {
                float mnew = fmaxf(mr, tmx);
                float scl = __builtin_amdgcn_exp2f(mr - mnew);
                lr *= scl;
#pragma unroll
                for (int r = 0; r < 16; ++r) { oa0[r] *= scl; oa1[r] *= scl; }
                mr = mnew;
            }

            // P = exp2(S - mr), bounded by 2^8
            f32x16 p0v;
#pragma unroll
            for (int r = 0; r < 16; ++r) p0v[r] = __builtin_amdgcn_exp2f(s0[r] - mr);
            float sm[8];
#pragma unroll
            for (int r = 0; r < 8; ++r) sm[r] = p0v[r] + p0v[r + 8];
#pragma unroll
            for (int r = 0; r < 4; ++r) sm[r] = sm[r] + sm[r + 4];
            float rs = (sm[0] + sm[1]) + (sm[2] + sm[3]);
            rs += __shfl_xor(rs, 32);
            lr += rs;

            // P -> LDS [q=l31][kv 0..31], packed via cvt_pk (low u16 = src0)
#pragma unroll
            for (int r4 = 0; r4 < 4; ++r4) {
                unsigned a0, a1;
                CVTPK(a0, p0v[r4 * 4 + 0], p0v[r4 * 4 + 1]);
                CVTPK(a1, p0v[r4 * 4 + 2], p0v[r4 * 4 + 3]);
                uint2 ua;
                ua.x = a0; ua.y = a1;
                *(uint2*)(Pw + l31 * PSTR2 + 8 * r4 + 4 * h5) = ua;
            }

            // PV: O^T[d][q] += V[d][kv] * P^T[kv][q]; kv range = w*32..w*32+31
#pragma unroll
            for (int s = 0; s < 2; ++s) {
                bf16x8 pf = *(const bf16x8*)(Pw + l31 * PSTR2 + 16 * s + 8 * h5);
                int ch = (((4 * w + 2 * s + h5) ^ (l31 & 7)) << 3);
                bf16x8 v0 = *(const bf16x8*)(sV + l31 * 64 + ch);
                bf16x8 v1 = *(const bf16x8*)(sV + (32 + l31) * 64 + ch);
                oa0 = MFMA32(v0, pf, oa0);
                oa1 = MFMA32(v1, pf, oa1);
            }
        }
        __syncthreads();   // all LDS reads done before next stage overwrites
    }

    // ---- merge the two kv-half partials (per-lane elementwise; same layout) ----
    float* xch = (float*)sKV;          // 64 lanes x 36 f32 = 9216 B (fits 16 KB)
    if (w == 1) {
        float* xl = xch + lane * 36;
#pragma unroll
        for (int r = 0; r < 16; ++r) { xl[r] = oa0[r]; xl[16 + r] = oa1[r]; }
        xl[32] = mr; xl[33] = lr;
    }
    __syncthreads();
    if (w == 0) {
        float* xl = xch + lane * 36;
        float m1 = xl[32], l1 = xl[33];
        float m = fmaxf(mr, m1);
        float e0 = __builtin_amdgcn_exp2f(mr - m);
        float e1 = __builtin_amdgcn_exp2f(m1 - m);
        float inv = 1.0f / (lr * e0 + l1 * e1);
        float f0 = e0 * inv, f1 = e1 * inv;

        u16* ob = O + (long)(b * TT + qg) * CC + h * SS;
#pragma unroll
        for (int rq = 0; rq < 4; ++rq) {
            float v00 = oa0[rq * 4 + 0] * f0 + xl[rq * 4 + 0] * f1;
            float v01 = oa0[rq * 4 + 1] * f0 + xl[rq * 4 + 1] * f1;
            float v02 = oa0[rq * 4 + 2] * f0 + xl[rq * 4 + 2] * f1;
            float v03 = oa0[rq * 4 + 3] * f0 + xl[rq * 4 + 3] * f1;
            float v10 = oa1[rq * 4 + 0] * f0 + xl[16 + rq * 4 + 0] * f1;
            float v11 = oa1[rq * 4 + 1] * f0 + xl[16 + rq * 4 + 1] * f1;
            float v12 = oa1[rq * 4 + 2] * f0 + xl[16 + rq * 4 + 2] * f1;
            float v13 = oa1[rq * 4 + 3] * f0 + xl[16 + rq * 4 + 3] * f1;
            unsigned a0, a1, c0, c1;
            CVTPK(a0, v00, v01);
            CVTPK(a1, v02, v03);
            CVTPK(c0, v10, v11);
            CVTPK(c1, v12, v13);
            uint2 ua, uc;
            ua.x = a0; ua.y = a1; uc.x = c0; uc.y = c1;
            *(uint2*)(ob + rq * 8 + h5 * 4) = ua;
            *(uint2*)(ob + 32 + rq * 8 + h5 * 4) = uc;
        }
    }
}

// ---------------------------------------------------------------- launch
extern "C" void kernel_launch(void* const* d_in, const int* in_sizes, int n_in,
                              void* d_out, int out_size, void* d_ws, size_t ws_size,
                              hipStream_t stream) {
    const float* x  = (const float*)d_in[0];
    const float* Wq = (const float*)d_in[1];
    const float* Wk = (const float*)d_in[2];
    const float* Wv = (const float*)d_in[3];
    const float* Wo = (const float*)d_in[4];
    const float* bo = (const float*)d_in[5];

    char* ws = (char*)d_ws;
    const size_t MB = 1024 * 1024;
    u16* x_bf  = (u16*)(ws);
    u16* wq_bf = (u16*)(ws + 8 * MB);
    u16* wk_bf = (u16*)(ws + 10 * MB);
    u16* wv_bf = (u16*)(ws + 12 * MB);
    u16* wo_bf = (u16*)(ws + 14 * MB);
    u16* q_bf  = (u16*)(ws + 16 * MB);
    u16* k_bf  = (u16*)(ws + 24 * MB);
    u16* vt_bf = (u16*)(ws + 32 * MB);   // [1024][4096] transposed V
    u16* at_bf = (u16*)(ws + 40 * MB);

    cast_all<<<dim3(8192), dim3(256), 0, stream>>>(
        (const float4*)x, (const float4*)Wq, (const float4*)Wk,
        (const float4*)Wv, (const float4*)Wo,
        (ushort4*)x_bf, (ushort4*)wq_bf, (ushort4*)wk_bf,
        (ushort4*)wv_bf, (ushort4*)wo_bf);

    qkv_gemm<<<dim3(768), dim3(256), 0, stream>>>(x_bf, wq_bf, wk_bf, wv_bf,
                                                  q_bf, k_bf, vt_bf);

    attn_fwd<<<dim3(2048), dim3(128), 0, stream>>>(q_bf, k_bf, vt_bf, at_bf);

    out_gemm<<<dim3(256), dim3(256), 0, stream>>>(at_bf, wo_bf, bo, (float*)d_out);
}